// Round 6
// baseline (1439.613 us; speedup 1.0000x reference)
//
#include <hip/hip_runtime.h>

#define IN_DIM 256
#define OUT_DIM 32
#define KITER 10

typedef __attribute__((ext_vector_type(8))) short short8v;   // 8 x bf16
typedef __attribute__((ext_vector_type(4))) float float4v;   // mfma C/D
typedef __attribute__((ext_vector_type(2))) float f2v;

__device__ __forceinline__ ushort f2bf(float f) {
    unsigned u = __float_as_uint(f);
    return (ushort)((u + 0x7fffu + ((u >> 16) & 1u)) >> 16);  // rne
}
__device__ __forceinline__ float bf2f(ushort s) {
    return __uint_as_float((unsigned)s << 16);
}

// ---------------- preprocessing ----------------

// per-node in-degree (for dinv)
__global__ void hist_kernel(const int* __restrict__ col, int E,
                            unsigned int* __restrict__ cnt) {
    int i = blockIdx.x * blockDim.x + threadIdx.x;
    if (i < E) atomicAdd(&cnt[col[i]], 1u);
}

__global__ void dinv_kernel(const unsigned int* __restrict__ cnt, int N,
                            float* __restrict__ dinv) {
    int i = blockIdx.x * blockDim.x + threadIdx.x;
    if (i < N) dinv[i] = rsqrtf((float)(cnt[i] + 1u));  // +1 self loop
}

// coarse-bucket histogram (bucket = col>>7), LDS-aggregated
#define HC_EDGES 4096
__global__ __launch_bounds__(256) void histC_kernel(const int* __restrict__ col, int E,
                                                    int nbc, unsigned int* __restrict__ cntC) {
    __shared__ unsigned int lh[1024];  // nbc <= 1024
    for (int i = threadIdx.x; i < nbc; i += 256) lh[i] = 0;
    __syncthreads();
    int base = blockIdx.x * HC_EDGES;
    int lim = min(base + HC_EDGES, E);
    for (int i = base + threadIdx.x; i < lim; i += 256) atomicAdd(&lh[col[i] >> 7], 1u);
    __syncthreads();
    for (int i = threadIdx.x; i < nbc; i += 256) {
        unsigned int v = lh[i];
        if (v) atomicAdd(&cntC[i], v);
    }
}

// serial scan of coarse counts -> base[nbc+1], cursor copy cur[nbc]
__global__ __launch_bounds__(256) void scanB_kernel(const unsigned int* __restrict__ cntC,
                                                    int nbc, unsigned int* __restrict__ base,
                                                    unsigned int* __restrict__ cur) {
    __shared__ unsigned int sh[1025];
    int t = threadIdx.x;
    for (int i = t; i < nbc; i += 256) sh[i] = cntC[i];
    __syncthreads();
    if (t == 0) {
        unsigned int run = 0;
        for (int i = 0; i < nbc; ++i) {
            unsigned int v = sh[i];
            sh[i] = run;
            run += v;
        }
        sh[nbc] = run;
    }
    __syncthreads();
    for (int i = t; i < nbc; i += 256) {
        base[i] = sh[i];
        cur[i] = sh[i];
    }
    if (t == 0) base[nbc] = sh[nbc];
}

// phase 1: bucket edges coarsely; writes temporally clustered -> near-full lines
__global__ void scatterC_kernel(const int* __restrict__ row, const int* __restrict__ col,
                                int E, unsigned int* __restrict__ curC,
                                uint2* __restrict__ tmp) {
    int e = blockIdx.x * blockDim.x + threadIdx.x;
    if (e >= E) return;
    int c = col[e];
    unsigned int p = atomicAdd(&curC[c >> 7], 1u);
    tmp[p] = make_uint2((unsigned)row[e], (unsigned)c);
}

// phase 2: per-bucket local sort; writes off[] and final (src, w) records
__global__ __launch_bounds__(256) void sortL_kernel(const uint2* __restrict__ tmp,
                                                    const unsigned int* __restrict__ cbase,
                                                    const float* __restrict__ dinv, int N,
                                                    int E, float2* __restrict__ ew,
                                                    unsigned int* __restrict__ off) {
    __shared__ unsigned int lh[128], lpref[128], lcur[128];
    int b = blockIdx.x;
    int t = threadIdx.x;
    unsigned int base = cbase[b], bend = cbase[b + 1];
    int c0 = b << 7;
    if (t < 128) lh[t] = 0;
    __syncthreads();
    for (unsigned int i = base + t; i < bend; i += 256) {
        atomicAdd(&lh[tmp[i].y - c0], 1u);
    }
    __syncthreads();
    if (t == 0) {
        unsigned int run = 0;
        for (int k = 0; k < 128; ++k) {
            lpref[k] = run;
            run += lh[k];
        }
    }
    __syncthreads();
    if (t < 128) {
        int node = c0 + t;
        if (node < N) off[node] = base + lpref[t];
        lcur[t] = 0;
    }
    if (b == 0 && t == 0) off[N] = (unsigned int)E;
    __syncthreads();
    for (unsigned int i = base + t; i < bend; i += 256) {
        uint2 sc = tmp[i];
        unsigned int tt = sc.y - c0;
        unsigned int p = base + lpref[tt] + atomicAdd(&lcur[tt], 1u);
        float2 v;
        v.x = __int_as_float((int)sc.x);
        v.y = dinv[sc.x] * dinv[sc.y];
        ew[p] = v;
    }
}

// ---------------- W -> bf16 hi/lo fragments (runs once, tiny) ----------------
__global__ __launch_bounds__(256) void wprep_kernel(const float* __restrict__ W,
                                                    short8v* __restrict__ Whi,
                                                    short8v* __restrict__ Wlo) {
    int t = blockIdx.x * 256 + threadIdx.x;  // 0..1023
    int n = t >> 9;
    int kc = (t >> 6) & 7;
    int l = t & 63;
    int ch = 16 * n + (l & 15);
    int k0 = kc * 32 + (l >> 4) * 8;
    const float* wp = W + ch * IN_DIM + k0;
    short8v hi, lo;
#pragma unroll
    for (int j = 0; j < 8; ++j) {
        float f = wp[j];
        unsigned u = __float_as_uint(f);
        hi[j] = (short)(u >> 16);
        float fh = __uint_as_float(u & 0xffff0000u);
        float r = f - fh;
        unsigned v = __float_as_uint(r);
        lo[j] = (short)((v + 0x7fffu + ((v >> 16) & 1u)) >> 16);
    }
    Whi[t] = hi;
    Wlo[t] = lo;
}

// ---------------- h = x @ W^T + b  (MFMA bf16 hi/lo, h stored bf16) ----------

__device__ __forceinline__ void cvt_hilo(float4 a, float4 c, short8v& hi, short8v& lo) {
    float f[8] = {a.x, a.y, a.z, a.w, c.x, c.y, c.z, c.w};
#pragma unroll
    for (int j = 0; j < 8; ++j) {
        unsigned u = __float_as_uint(f[j]);
        hi[j] = (short)(u >> 16);
        float fh = __uint_as_float(u & 0xffff0000u);
        float r = f[j] - fh;
        unsigned v = __float_as_uint(r);
        lo[j] = (short)((v + 0x7fffu + ((v >> 16) & 1u)) >> 16);
    }
}

__global__ __launch_bounds__(256) void gemm_kernel(const float* __restrict__ x,
                                                   const short8v* __restrict__ Whi,
                                                   const short8v* __restrict__ Wlo,
                                                   const float* __restrict__ b, int N,
                                                   ushort* __restrict__ h) {
    int wid = threadIdx.x >> 6;
    int l = threadIdx.x & 63;
    int lr = l & 15;
    int lk = l >> 4;
    int r0 = blockIdx.x * 256 + wid * 64;

    int arow[4];
#pragma unroll
    for (int m = 0; m < 4; ++m) {
        int r = r0 + 16 * m + lr;
        arow[m] = (r < N) ? r : (N - 1);
    }

    float4v acc[4][2];
#pragma unroll
    for (int m = 0; m < 4; ++m)
#pragma unroll
        for (int n = 0; n < 2; ++n) acc[m][n] = (float4v)(0.0f);

#pragma unroll
    for (int kc = 0; kc < 8; ++kc) {
        short8v bh0 = Whi[(0 * 8 + kc) * 64 + l];
        short8v bh1 = Whi[(1 * 8 + kc) * 64 + l];
        short8v bl0 = Wlo[(0 * 8 + kc) * 64 + l];
        short8v bl1 = Wlo[(1 * 8 + kc) * 64 + l];
#pragma unroll
        for (int m = 0; m < 4; ++m) {
            const float* xp = x + (size_t)arow[m] * IN_DIM + kc * 32 + lk * 8;
            float4 xa = *(const float4*)xp;
            float4 xc = *(const float4*)(xp + 4);
            short8v ah, al;
            cvt_hilo(xa, xc, ah, al);
            acc[m][0] = __builtin_amdgcn_mfma_f32_16x16x32_bf16(ah, bh0, acc[m][0], 0, 0, 0);
            acc[m][1] = __builtin_amdgcn_mfma_f32_16x16x32_bf16(ah, bh1, acc[m][1], 0, 0, 0);
            acc[m][0] = __builtin_amdgcn_mfma_f32_16x16x32_bf16(al, bh0, acc[m][0], 0, 0, 0);
            acc[m][1] = __builtin_amdgcn_mfma_f32_16x16x32_bf16(al, bh1, acc[m][1], 0, 0, 0);
            acc[m][0] = __builtin_amdgcn_mfma_f32_16x16x32_bf16(ah, bl0, acc[m][0], 0, 0, 0);
            acc[m][1] = __builtin_amdgcn_mfma_f32_16x16x32_bf16(ah, bl1, acc[m][1], 0, 0, 0);
        }
    }

    float bb[2];
    bb[0] = b[lr];
    bb[1] = b[16 + lr];
#pragma unroll
    for (int m = 0; m < 4; ++m) {
#pragma unroll
        for (int n = 0; n < 2; ++n) {
            int ch = 16 * n + lr;
#pragma unroll
            for (int reg = 0; reg < 4; ++reg) {
                int row = r0 + 16 * m + 4 * lk + reg;
                if (row < N) h[(size_t)row * OUT_DIM + ch] = f2bf(acc[m][n][reg] + bb[n]);
            }
        }
    }
}

// ---------------- one APPNP propagation step ----------------
// ONE node per 64-lane wave: two 32-lane halves split the edge list (ch = lane&31),
// 8-deep gather pipeline per half, shfl_xor(32) combine. nt hints keep L2 for z.

template <bool OUT_BF>
__global__ __launch_bounds__(256) void spmv_kernel(
    const float2* __restrict__ ew, const unsigned int* __restrict__ off,
    const float* __restrict__ dinv, const ushort* __restrict__ zin,
    const ushort* __restrict__ hbf, const float* __restrict__ prelu_a, int N,
    void* __restrict__ zout_v) {
    int lane = threadIdx.x & 63;
    int ch = lane & 31;
    int half = lane >> 5;
    int node = blockIdx.x * 4 + (threadIdx.x >> 6);
    if (node >= N) return;
    unsigned nidx = (unsigned)node * OUT_DIM + ch;
    unsigned e0 = off[node];
    int cnt = (int)(off[node + 1] - e0);
    int myCnt = (cnt - half + 1) >> 1;  // half0: ceil, half1: floor
    float di = dinv[node];
    float self = bf2f(zin[nidx]);
    float hterm = 0.2f * bf2f(__builtin_nontemporal_load(&hbf[nidx]));
    float a0 = half ? 0.f : di * di * self;
    float a1 = 0.f, a2 = 0.f, a3 = 0.f;
    const f2v* ewp = (const f2v*)ew;
    unsigned base = e0 + half;

    int j = 0;
    for (; j + 8 <= myCnt; j += 8) {
        f2v p[8];
#pragma unroll
        for (int k = 0; k < 8; ++k)
            p[k] = __builtin_nontemporal_load(ewp + base + 2u * (j + k));
        float zv[8];
#pragma unroll
        for (int k = 0; k < 8; ++k)
            zv[k] = bf2f(zin[(unsigned)__float_as_int(p[k].x) * OUT_DIM + ch]);
#pragma unroll
        for (int k = 0; k < 8; ++k) {
            float t = p[k].y * zv[k];
            if ((k & 3) == 0) a0 += t;
            else if ((k & 3) == 1) a1 += t;
            else if ((k & 3) == 2) a2 += t;
            else a3 += t;
        }
    }
    for (; j < myCnt; ++j) {
        f2v p = __builtin_nontemporal_load(ewp + base + 2u * j);
        a0 += p.y * bf2f(zin[(unsigned)__float_as_int(p.x) * OUT_DIM + ch]);
    }

    float sum = (a0 + a1) + (a2 + a3);
    sum += __shfl_xor(sum, 32);
    float out = 0.8f * sum + hterm;
    if (OUT_BF) {
        if (half == 0)
            __builtin_nontemporal_store(f2bf(out), (ushort*)zout_v + nidx);
    } else {
        float a = prelu_a[ch];
        out = (out >= 0.f) ? out : a * out;
        if (half == 0) __builtin_nontemporal_store(out, (float*)zout_v + nidx);
    }
}

// ---------------- launcher ----------------

extern "C" void kernel_launch(void* const* d_in, const int* in_sizes, int n_in,
                              void* d_out, int out_size, void* d_ws, size_t ws_size,
                              hipStream_t stream) {
    const float* x = (const float*)d_in[0];
    const int* ei = (const int*)d_in[1];
    const float* W = (const float*)d_in[2];
    const float* b = (const float*)d_in[3];
    const float* pa = (const float*)d_in[4];

    int N = in_sizes[0] / IN_DIM;
    int E = in_sizes[1] / 2;
    const int* row = ei;      // edge_index[0] = source
    const int* col = ei + E;  // edge_index[1] = target
    int nbc = (N + 127) / 128;  // coarse buckets (<=1024 for N<=131072)

    char* ws = (char*)d_ws;
    size_t o = 0;
    auto alloc = [&](size_t bytes) -> void* {
        void* p = ws + o;
        o += (bytes + 255) & ~(size_t)255;
        return p;
    };
    unsigned int* d_cnt = (unsigned int*)alloc((size_t)N * 4);
    float* d_dinv = (float*)alloc((size_t)N * 4);
    unsigned int* d_cntC = (unsigned int*)alloc((size_t)(nbc + 1) * 4);
    unsigned int* d_cbase = (unsigned int*)alloc((size_t)(nbc + 1) * 4);
    unsigned int* d_curC = (unsigned int*)alloc((size_t)(nbc + 1) * 4);
    unsigned int* d_off = (unsigned int*)alloc((size_t)(N + 1) * 4);
    uint2* d_tmp = (uint2*)alloc((size_t)E * 8);
    float2* d_ew = (float2*)alloc((size_t)E * 8);
    ushort* d_h = (ushort*)alloc((size_t)N * OUT_DIM * 2);
    ushort* d_zA = (ushort*)alloc((size_t)N * OUT_DIM * 2);
    ushort* d_zB = (ushort*)alloc((size_t)N * OUT_DIM * 2);
    short8v* d_Whi = (short8v*)alloc(16384);
    short8v* d_Wlo = (short8v*)alloc(16384);
    (void)ws_size;

    hipMemsetAsync(d_cnt, 0, (size_t)N * 4, stream);
    hipMemsetAsync(d_cntC, 0, (size_t)(nbc + 1) * 4, stream);

    hist_kernel<<<(E + 255) / 256, 256, 0, stream>>>(col, E, d_cnt);
    dinv_kernel<<<(N + 255) / 256, 256, 0, stream>>>(d_cnt, N, d_dinv);
    histC_kernel<<<(E + HC_EDGES - 1) / HC_EDGES, 256, 0, stream>>>(col, E, nbc, d_cntC);
    scanB_kernel<<<1, 256, 0, stream>>>(d_cntC, nbc, d_cbase, d_curC);
    scatterC_kernel<<<(E + 255) / 256, 256, 0, stream>>>(row, col, E, d_curC, d_tmp);
    sortL_kernel<<<nbc, 256, 0, stream>>>(d_tmp, d_cbase, d_dinv, N, E, d_ew, d_off);
    wprep_kernel<<<4, 256, 0, stream>>>(W, d_Whi, d_Wlo);
    gemm_kernel<<<(N + 255) / 256, 256, 0, stream>>>(x, d_Whi, d_Wlo, b, N, d_h);

    int grid = (N + 3) / 4;
    // iter 0: zin = h (bf16)
    spmv_kernel<true><<<grid, 256, 0, stream>>>(d_ew, d_off, d_dinv, d_h, d_h, pa, N, d_zA);
    ushort* bufs[2] = {d_zA, d_zB};
    for (int it = 1; it < KITER - 1; ++it) {
        spmv_kernel<true><<<grid, 256, 0, stream>>>(d_ew, d_off, d_dinv, bufs[(it + 1) & 1],
                                                    d_h, pa, N, bufs[it & 1]);
    }
    // iter 9: write f32 out + PReLU
    spmv_kernel<false><<<grid, 256, 0, stream>>>(d_ew, d_off, d_dinv, bufs[1], d_h, pa, N,
                                                 d_out);
}

// Round 7
// 630.458 us; speedup vs baseline: 2.2834x; 2.2834x over previous
//
#include <hip/hip_runtime.h>

#define IN_DIM 256
#define OUT_DIM 32
#define KITER 10
#define SCAN_TILE 2048

typedef __attribute__((ext_vector_type(8))) short short8v;   // 8 x bf16
typedef __attribute__((ext_vector_type(4))) float float4v;   // mfma C/D

__device__ __forceinline__ ushort f2bf(float f) {
    unsigned u = __float_as_uint(f);
    return (ushort)((u + 0x7fffu + ((u >> 16) & 1u)) >> 16);  // rne
}
__device__ __forceinline__ float bfLo(unsigned u) {            // low ushort -> float
    return __uint_as_float(u << 16);
}
__device__ __forceinline__ float bfHi(unsigned u) {            // high ushort -> float
    return __uint_as_float(u & 0xffff0000u);
}

// ---------------- preprocessing ----------------

__global__ void hist_kernel(const int* __restrict__ col, int E,
                            unsigned int* __restrict__ cnt) {
    int i = blockIdx.x * blockDim.x + threadIdx.x;
    if (i < E) atomicAdd(&cnt[col[i]], 1u);
}

// per-tile local exclusive scan (+ tile sums + fused dinv)
__global__ __launch_bounds__(256) void scanA_kernel(const unsigned int* __restrict__ cnt,
                                                    int N, unsigned int* __restrict__ local,
                                                    unsigned int* __restrict__ blkSum,
                                                    float* __restrict__ dinv) {
    __shared__ unsigned int sh[256];
    int t = threadIdx.x;
    int base = blockIdx.x * SCAN_TILE + t * 8;
    unsigned int v[8];
    unsigned int sum = 0;
#pragma unroll
    for (int i = 0; i < 8; ++i) {
        int idx = base + i;
        v[i] = (idx < N) ? cnt[idx] : 0u;
        sum += v[i];
    }
    sh[t] = sum;
    __syncthreads();
#pragma unroll
    for (int d = 1; d < 256; d <<= 1) {
        unsigned int x = (t >= d) ? sh[t - d] : 0u;
        __syncthreads();
        sh[t] += x;
        __syncthreads();
    }
    if (t == 255) blkSum[blockIdx.x] = sh[255];
    unsigned int run = (t > 0) ? sh[t - 1] : 0u;
#pragma unroll
    for (int i = 0; i < 8; ++i) {
        int idx = base + i;
        if (idx < N) {
            local[idx] = run;
            run += v[i];
            dinv[idx] = rsqrtf((float)(v[i] + 1u));  // +1 self loop
        }
    }
}

__global__ __launch_bounds__(256) void scanB_kernel(unsigned int* __restrict__ blkSum, int nb) {
    __shared__ unsigned int sh[1025];
    int t = threadIdx.x;
    for (int i = t; i < nb; i += 256) sh[i] = blkSum[i];
    __syncthreads();
    if (t == 0) {
        unsigned int run = 0;
        for (int i = 0; i < nb; ++i) {
            unsigned int x = sh[i];
            sh[i] = run;
            run += x;
        }
        sh[nb] = run;
    }
    __syncthreads();
    for (int i = t; i <= nb; i += 256) blkSum[i] = sh[i];
}

__global__ void scanC_kernel(const unsigned int* __restrict__ local,
                             const unsigned int* __restrict__ blkSum, int N, int nb,
                             unsigned int* __restrict__ off, unsigned int* __restrict__ cur) {
    int i = blockIdx.x * blockDim.x + threadIdx.x;
    if (i < N) {
        unsigned int v = local[i] + blkSum[i / SCAN_TILE];
        off[i] = v;
        cur[i] = v;
    } else if (i == N) {
        off[N] = blkSum[nb];
    }
}

// direct scatter, src-only 4B records (weights factored out via zs = dinv*z)
__global__ void scatter_kernel(const int* __restrict__ row, const int* __restrict__ col,
                               int E, unsigned int* __restrict__ cur,
                               int* __restrict__ srcs) {
    int e = blockIdx.x * blockDim.x + threadIdx.x;
    if (e >= E) return;
    unsigned int p = atomicAdd(&cur[col[e]], 1u);
    srcs[p] = row[e];
}

// ---------------- W -> bf16 hi/lo fragments (runs once, tiny) ----------------
__global__ __launch_bounds__(256) void wprep_kernel(const float* __restrict__ W,
                                                    short8v* __restrict__ Whi,
                                                    short8v* __restrict__ Wlo) {
    int t = blockIdx.x * 256 + threadIdx.x;  // 0..1023
    int n = t >> 9;
    int kc = (t >> 6) & 7;
    int l = t & 63;
    int ch = 16 * n + (l & 15);
    int k0 = kc * 32 + (l >> 4) * 8;
    const float* wp = W + ch * IN_DIM + k0;
    short8v hi, lo;
#pragma unroll
    for (int j = 0; j < 8; ++j) {
        float f = wp[j];
        unsigned u = __float_as_uint(f);
        hi[j] = (short)(u >> 16);
        float fh = __uint_as_float(u & 0xffff0000u);
        float r = f - fh;
        unsigned v = __float_as_uint(r);
        lo[j] = (short)((v + 0x7fffu + ((v >> 16) & 1u)) >> 16);
    }
    Whi[t] = hi;
    Wlo[t] = lo;
}

// ---------------- h = x @ W^T + b  (MFMA bf16 hi/lo) -------------------------
// writes hbf (bf16 h) and zs0 (bf16 dinv*h)

__device__ __forceinline__ void cvt_hilo(float4 a, float4 c, short8v& hi, short8v& lo) {
    float f[8] = {a.x, a.y, a.z, a.w, c.x, c.y, c.z, c.w};
#pragma unroll
    for (int j = 0; j < 8; ++j) {
        unsigned u = __float_as_uint(f[j]);
        hi[j] = (short)(u >> 16);
        float fh = __uint_as_float(u & 0xffff0000u);
        float r = f[j] - fh;
        unsigned v = __float_as_uint(r);
        lo[j] = (short)((v + 0x7fffu + ((v >> 16) & 1u)) >> 16);
    }
}

__global__ __launch_bounds__(256) void gemm_kernel(const float* __restrict__ x,
                                                   const short8v* __restrict__ Whi,
                                                   const short8v* __restrict__ Wlo,
                                                   const float* __restrict__ b,
                                                   const float* __restrict__ dinv, int N,
                                                   ushort* __restrict__ hbf,
                                                   ushort* __restrict__ zs0) {
    int wid = threadIdx.x >> 6;
    int l = threadIdx.x & 63;
    int lr = l & 15;
    int lk = l >> 4;
    int r0 = blockIdx.x * 256 + wid * 64;

    int arow[4];
#pragma unroll
    for (int m = 0; m < 4; ++m) {
        int r = r0 + 16 * m + lr;
        arow[m] = (r < N) ? r : (N - 1);
    }

    float4v acc[4][2];
#pragma unroll
    for (int m = 0; m < 4; ++m)
#pragma unroll
        for (int n = 0; n < 2; ++n) acc[m][n] = (float4v)(0.0f);

#pragma unroll
    for (int kc = 0; kc < 8; ++kc) {
        short8v bh0 = Whi[(0 * 8 + kc) * 64 + l];
        short8v bh1 = Whi[(1 * 8 + kc) * 64 + l];
        short8v bl0 = Wlo[(0 * 8 + kc) * 64 + l];
        short8v bl1 = Wlo[(1 * 8 + kc) * 64 + l];
#pragma unroll
        for (int m = 0; m < 4; ++m) {
            const float* xp = x + (size_t)arow[m] * IN_DIM + kc * 32 + lk * 8;
            float4 xa = *(const float4*)xp;
            float4 xc = *(const float4*)(xp + 4);
            short8v ah, al;
            cvt_hilo(xa, xc, ah, al);
            acc[m][0] = __builtin_amdgcn_mfma_f32_16x16x32_bf16(ah, bh0, acc[m][0], 0, 0, 0);
            acc[m][1] = __builtin_amdgcn_mfma_f32_16x16x32_bf16(ah, bh1, acc[m][1], 0, 0, 0);
            acc[m][0] = __builtin_amdgcn_mfma_f32_16x16x32_bf16(al, bh0, acc[m][0], 0, 0, 0);
            acc[m][1] = __builtin_amdgcn_mfma_f32_16x16x32_bf16(al, bh1, acc[m][1], 0, 0, 0);
            acc[m][0] = __builtin_amdgcn_mfma_f32_16x16x32_bf16(ah, bl0, acc[m][0], 0, 0, 0);
            acc[m][1] = __builtin_amdgcn_mfma_f32_16x16x32_bf16(ah, bl1, acc[m][1], 0, 0, 0);
        }
    }

    float bb[2];
    bb[0] = b[lr];
    bb[1] = b[16 + lr];
#pragma unroll
    for (int m = 0; m < 4; ++m) {
#pragma unroll
        for (int n = 0; n < 2; ++n) {
            int ch = 16 * n + lr;
#pragma unroll
            for (int reg = 0; reg < 4; ++reg) {
                int row = r0 + 16 * m + 4 * lk + reg;
                if (row < N) {
                    float v = acc[m][n][reg] + bb[n];
                    size_t idx = (size_t)row * OUT_DIM + ch;
                    hbf[idx] = f2bf(v);
                    zs0[idx] = f2bf(dinv[row] * v);
                }
            }
        }
    }
}

// ---------------- one APPNP propagation step (zs-form) ----------------
// 16 lanes per node, 2 channels/lane (ushort2 gathers). 8-deep pipeline.
// z' = 0.8*dinv[c]*(sum zs[src] + zs[self]) + 0.2*h ; zs' = dinv[c]*z'

template <bool LAST>
__global__ __launch_bounds__(256) void spmv_kernel(
    const int* __restrict__ srcs, const unsigned int* __restrict__ off,
    const float* __restrict__ dinv, const unsigned int* __restrict__ zsin,
    const unsigned int* __restrict__ hbf2, const float* __restrict__ prelu_a, int N,
    unsigned int* __restrict__ zsout, float2* __restrict__ outf) {
    int ch2 = threadIdx.x & 15;                      // channel pair
    int node = blockIdx.x * 16 + (threadIdx.x >> 4);
    if (node >= N) return;
    unsigned nidx = (unsigned)node * 16 + ch2;
    unsigned e = off[node];
    unsigned end = off[node + 1];
    float dc = dinv[node];
    unsigned selfu = zsin[nidx];
    unsigned hu = hbf2[nidx];
    float aL0 = bfLo(selfu), aH0 = bfHi(selfu);      // self-loop zs
    float aL1 = 0.f, aH1 = 0.f;

    while (e + 8 <= end) {
        int s[8];
#pragma unroll
        for (int k = 0; k < 8; ++k) s[k] = srcs[e + k];
        unsigned g[8];
#pragma unroll
        for (int k = 0; k < 8; ++k) g[k] = zsin[(unsigned)s[k] * 16 + ch2];
#pragma unroll
        for (int k = 0; k < 8; ++k) {
            if (k & 1) {
                aL1 += bfLo(g[k]);
                aH1 += bfHi(g[k]);
            } else {
                aL0 += bfLo(g[k]);
                aH0 += bfHi(g[k]);
            }
        }
        e += 8;
    }
    while (e + 2 <= end) {
        int s0 = srcs[e], s1 = srcs[e + 1];
        unsigned g0 = zsin[(unsigned)s0 * 16 + ch2];
        unsigned g1 = zsin[(unsigned)s1 * 16 + ch2];
        aL0 += bfLo(g0);
        aH0 += bfHi(g0);
        aL1 += bfLo(g1);
        aH1 += bfHi(g1);
        e += 2;
    }
    if (e < end) {
        unsigned g = zsin[(unsigned)srcs[e] * 16 + ch2];
        aL0 += bfLo(g);
        aH0 += bfHi(g);
    }

    float zLo = 0.8f * dc * (aL0 + aL1) + 0.2f * bfLo(hu);
    float zHi = 0.8f * dc * (aH0 + aH1) + 0.2f * bfHi(hu);
    if (LAST) {
        float2 pa = ((const float2*)prelu_a)[ch2];
        float2 o;
        o.x = (zLo >= 0.f) ? zLo : pa.x * zLo;
        o.y = (zHi >= 0.f) ? zHi : pa.y * zHi;
        outf[nidx] = o;
    } else {
        unsigned r = (unsigned)f2bf(dc * zLo) | ((unsigned)f2bf(dc * zHi) << 16);
        zsout[nidx] = r;
    }
}

// ---------------- launcher ----------------

extern "C" void kernel_launch(void* const* d_in, const int* in_sizes, int n_in,
                              void* d_out, int out_size, void* d_ws, size_t ws_size,
                              hipStream_t stream) {
    const float* x = (const float*)d_in[0];
    const int* ei = (const int*)d_in[1];
    const float* W = (const float*)d_in[2];
    const float* b = (const float*)d_in[3];
    const float* pa = (const float*)d_in[4];

    int N = in_sizes[0] / IN_DIM;
    int E = in_sizes[1] / 2;
    const int* row = ei;      // edge_index[0] = source
    const int* col = ei + E;  // edge_index[1] = target
    int nb = (N + SCAN_TILE - 1) / SCAN_TILE;

    char* ws = (char*)d_ws;
    size_t o = 0;
    auto alloc = [&](size_t bytes) -> void* {
        void* p = ws + o;
        o += (bytes + 255) & ~(size_t)255;
        return p;
    };
    unsigned int* d_cnt = (unsigned int*)alloc((size_t)N * 4);
    unsigned int* d_local = (unsigned int*)alloc((size_t)N * 4);
    unsigned int* d_blkSum = (unsigned int*)alloc(4096);
    unsigned int* d_off = (unsigned int*)alloc((size_t)(N + 1) * 4);
    unsigned int* d_cur = (unsigned int*)alloc((size_t)N * 4);
    float* d_dinv = (float*)alloc((size_t)N * 4);
    int* d_srcs = (int*)alloc((size_t)E * 4);
    ushort* d_h = (ushort*)alloc((size_t)N * OUT_DIM * 2);
    ushort* d_zsA = (ushort*)alloc((size_t)N * OUT_DIM * 2);
    ushort* d_zsB = (ushort*)alloc((size_t)N * OUT_DIM * 2);
    short8v* d_Whi = (short8v*)alloc(16384);
    short8v* d_Wlo = (short8v*)alloc(16384);
    (void)ws_size;

    hipMemsetAsync(d_cnt, 0, (size_t)N * 4, stream);

    hist_kernel<<<(E + 255) / 256, 256, 0, stream>>>(col, E, d_cnt);
    scanA_kernel<<<nb, 256, 0, stream>>>(d_cnt, N, d_local, d_blkSum, d_dinv);
    scanB_kernel<<<1, 256, 0, stream>>>(d_blkSum, nb);
    scanC_kernel<<<(N + 256) / 256, 256, 0, stream>>>(d_local, d_blkSum, N, nb, d_off, d_cur);
    scatter_kernel<<<(E + 255) / 256, 256, 0, stream>>>(row, col, E, d_cur, d_srcs);
    wprep_kernel<<<4, 256, 0, stream>>>(W, d_Whi, d_Wlo);
    gemm_kernel<<<(N + 255) / 256, 256, 0, stream>>>(x, d_Whi, d_Wlo, b, d_dinv, N, d_h,
                                                     d_zsA);

    int grid = (N + 15) / 16;
    // iters 0..8: zs -> zs (bf16); iter 9: f32 out + PReLU
    unsigned int* bufs[2] = {(unsigned int*)d_zsA, (unsigned int*)d_zsB};
    for (int it = 0; it < KITER - 1; ++it) {
        spmv_kernel<false><<<grid, 256, 0, stream>>>(
            d_srcs, d_off, d_dinv, bufs[it & 1], (const unsigned int*)d_h, pa, N,
            bufs[(it + 1) & 1], nullptr);
    }
    spmv_kernel<true><<<grid, 256, 0, stream>>>(d_srcs, d_off, d_dinv, bufs[(KITER - 1) & 1],
                                                (const unsigned int*)d_h, pa, N, nullptr,
                                                (float2*)d_out);
}